// Round 1
// baseline (200.689 us; speedup 1.0000x reference)
//
#include <hip/hip_runtime.h>

#define N_SP 16384
#define C_DIM 128
#define K_DIM 32

typedef short short8 __attribute__((ext_vector_type(8)));
typedef float f32x16 __attribute__((ext_vector_type(16)));
static_assert(sizeof(short8) == 16, "short8 must be 16B");

__device__ __forceinline__ unsigned short f2bf(float f){
    unsigned int u = __float_as_uint(f);
    u = u + 0x7FFFu + ((u >> 16) & 1u);   // RNE round to bf16
    return (unsigned short)(u >> 16);
}

// swizzled index into a [row][128] ushort LDS tile: XOR bits 3..5 with row&7
// (16-byte granular in byte-space -> b128 reads stay contiguous & conflict-spread)
#define SWZ(row, n) ((((row) * 128) + (n)) ^ (((row) & 7) << 3))

__global__ __launch_bounds__(128) void enc_main(
    const float* __restrict__ x,      // [B][C][N]
    const float* __restrict__ cwt2,   // [C][K] = -2*scale[k]*cw[k][c]
    const float* __restrict__ scale,  // [K]
    const float* __restrict__ sc2,    // [K] = scale[k]*||cw_k||^2
    float* __restrict__ wxacc,        // [B][K][C] (zeroed)
    float* __restrict__ wsacc)        // [B][K]    (zeroed)
{
    __shared__ unsigned short xs[C_DIM * 128];   // bf16 x[c][n'] swizzled (32 KB)
    __shared__ unsigned short aws[K_DIM * 128];  // bf16 aw[k][n'] swizzled (8 KB)

    const int t   = threadIdx.x;     // 0..127
    const int b   = blockIdx.y;
    const int l   = t & 63;
    const int w   = t >> 6;          // wave id (0..1)
    const int hi  = l >> 5;
    const int l31 = l & 31;

    const float* xb = x + (size_t)b * C_DIM * N_SP;

    f32x16 acc0, acc1, accS;
#pragma unroll
    for (int i = 0; i < 16; ++i){ acc0[i] = 0.f; acc1[i] = 0.f; accS[i] = 0.f; }

    short8 ones;
#pragma unroll
    for (int i = 0; i < 8; ++i) ones[i] = (short)0x3F80;  // bf16 1.0

    // wave w owns output c-tiles 2w and 2w+1
    const int c_a = (2 * w) * 32 + l31;
    const int c_b = c_a + 32;

    for (int tile = 0; tile < 2; ++tile){
        const int n0 = blockIdx.x * 256 + tile * 128;
        __syncthreads();   // protect xs/aws from previous tile's MFMA readers

        // ---- phase 1: stream x, fp32 distance dot-products, stage bf16 tile ----
        float xc[K_DIM];
#pragma unroll
        for (int k = 0; k < K_DIM; ++k) xc[k] = 0.f;
        float x2 = 0.f;

#pragma unroll 2
        for (int c = 0; c < C_DIM; ++c){
            float xv = xb[c * N_SP + n0 + t];        // coalesced dword
            x2 = fmaf(xv, xv, x2);
            xs[SWZ(c, t)] = f2bf(xv);
            const float* cwc = cwt2 + (c << 5);      // wave-uniform address
#pragma unroll
            for (int k = 0; k < K_DIM; ++k)
                xc[k] = fmaf(xv, cwc[k], xc[k]);
        }

        // ---- phase 2: per-thread softmax over k ----
        float m = -3.4e38f;
#pragma unroll
        for (int k = 0; k < K_DIM; ++k){
            float s = fmaf(scale[k], x2, xc[k] + sc2[k]);  // scale*(x2 - 2x.cw + c2)
            xc[k] = s;
            m = fmaxf(m, s);
        }
        float sum = 0.f;
#pragma unroll
        for (int k = 0; k < K_DIM; ++k){
            float p = __expf(xc[k] - m);
            xc[k] = p;
            sum += p;
        }
        float r = 1.f / sum;
#pragma unroll
        for (int k = 0; k < K_DIM; ++k)
            aws[SWZ(k, t)] = f2bf(xc[k] * r);

        __syncthreads();

        // ---- phase 3: wx[k][c] += aw[k][n] * x[n][c] via MFMA ----
#pragma unroll
        for (int nch = 0; nch < 8; ++nch){
            const int n8 = nch * 16 + hi * 8;   // K-dim (n) elems for this lane
            short8 af  = *(const short8*)(const void*)&aws[SWZ(l31, n8)];
            short8 bf0 = *(const short8*)(const void*)&xs[SWZ(c_a, n8)];
            short8 bf1 = *(const short8*)(const void*)&xs[SWZ(c_b, n8)];
            acc0 = __builtin_amdgcn_mfma_f32_32x32x16_bf16(af, bf0, acc0, 0, 0, 0);
            acc1 = __builtin_amdgcn_mfma_f32_32x32x16_bf16(af, bf1, acc1, 0, 0, 0);
            if (w == 0)
                accS = __builtin_amdgcn_mfma_f32_32x32x16_bf16(af, ones, accS, 0, 0, 0);
        }
    }

    // ---- epilogue: atomic-reduce block partials to global ----
    float* wxb = wxacc + (size_t)b * K_DIM * C_DIM;
#pragma unroll
    for (int rg = 0; rg < 16; ++rg){
        const int row = (rg & 3) + 8 * (rg >> 2) + 4 * hi;  // verified D layout
        atomicAdd(&wxb[row * C_DIM + c_a], acc0[rg]);
        atomicAdd(&wxb[row * C_DIM + c_b], acc1[rg]);
    }
    if (w == 0 && l31 == 0){
#pragma unroll
        for (int rg = 0; rg < 16; ++rg){
            const int row = (rg & 3) + 8 * (rg >> 2) + 4 * hi;
            atomicAdd(&wsacc[b * K_DIM + row], accS[rg]);
        }
    }
}

__global__ void enc_prep(const float* __restrict__ cw, const float* __restrict__ scale,
                         float* __restrict__ cwt2, float* __restrict__ sc2){
    const int t = threadIdx.x;  // 128 threads; t = c
    for (int k = 0; k < K_DIM; ++k)
        cwt2[t * K_DIM + k] = -2.f * scale[k] * cw[k * C_DIM + t];
    if (t < K_DIM){
        float s = 0.f;
        for (int c = 0; c < C_DIM; ++c){
            float v = cw[t * C_DIM + c];
            s = fmaf(v, v, s);
        }
        sc2[t] = scale[t] * s;
    }
}

__global__ void enc_final(const float* __restrict__ wxacc, const float* __restrict__ wsacc,
                          const float* __restrict__ cw, float* __restrict__ out){
    const int i  = blockIdx.x * 256 + threadIdx.x;  // B*K*C = 131072
    const int c  = i & (C_DIM - 1);
    const int kk = (i >> 7) & (K_DIM - 1);
    const int bk = i >> 7;
    out[i] = wxacc[i] - wsacc[bk] * cw[kk * C_DIM + c];
}

extern "C" void kernel_launch(void* const* d_in, const int* in_sizes, int n_in,
                              void* d_out, int out_size, void* d_ws, size_t ws_size,
                              hipStream_t stream){
    (void)in_sizes; (void)n_in; (void)out_size; (void)ws_size;
    const float* x     = (const float*)d_in[0];
    const float* cw    = (const float*)d_in[1];
    const float* scale = (const float*)d_in[2];
    float* out = (float*)d_out;

    float* wxacc = (float*)d_ws;                 // 32*32*128 f32
    float* wsacc = wxacc + 32 * 32 * 128;        // 32*32
    float* cwt2  = wsacc + 32 * 32;              // 128*32
    float* sc2   = cwt2 + 128 * 32;              // 32

    hipMemsetAsync(wxacc, 0, (32 * 32 * 128 + 32 * 32) * sizeof(float), stream);
    enc_prep<<<1, 128, 0, stream>>>(cw, scale, cwt2, sc2);
    enc_main<<<dim3(64, 32), 128, 0, stream>>>(x, cwt2, scale, sc2, wxacc, wsacc);
    enc_final<<<512, 256, 0, stream>>>(wxacc, wsacc, cw, out);
}

// Round 2
// 131.454 us; speedup vs baseline: 1.5267x; 1.5267x over previous
//
#include <hip/hip_runtime.h>

#define N_SP 16384
#define C_DIM 128
#define K_DIM 32
#define NBX   32      // blocks along n
#define TILES 4       // 128-n tiles per block; NBX*TILES*128 == N_SP

typedef short short8 __attribute__((ext_vector_type(8)));
typedef float f32x16 __attribute__((ext_vector_type(16)));

__device__ __forceinline__ unsigned short f2bf(float f){
    unsigned int u = __float_as_uint(f);
    return (unsigned short)((u + 0x8000u) >> 16);   // round-to-nearest (cheap)
}

// swizzled index into a [row][128] ushort LDS tile: XOR bits 3..5 of n with row&7
// -> b128 reads stay 16B-contiguous, rows spread across bank groups
#define SWZ(row, n) ((((row) * 128) + (n)) ^ (((row) & 7) << 3))

__global__ __launch_bounds__(128) void enc_main(
    const float* __restrict__ x,      // [B][C][N]
    const float* __restrict__ cwt2,   // [C][K] = -2*scale[k]*cw[k][c]
    const float* __restrict__ scale,  // [K]
    const float* __restrict__ sc2,    // [K] = scale[k]*||cw_k||^2
    float* __restrict__ wxacc,        // [B][K][C] (zeroed)
    float* __restrict__ wsacc)        // [B][K]    (zeroed)
{
    __shared__ unsigned short xs[C_DIM * 128];   // bf16 x[c][n'] swizzled (32 KB)
    __shared__ unsigned short aws[K_DIM * 128];  // bf16 aw[k][n'] swizzled (8 KB)

    const int t   = threadIdx.x;     // 0..127
    const int b   = blockIdx.y;
    const int l   = t & 63;
    const int w   = t >> 6;          // wave id (0..1)
    const int hi  = l >> 5;
    const int l31 = l & 31;

    const float* xb = x + (size_t)b * C_DIM * N_SP;

    f32x16 acc0, acc1, accS;
#pragma unroll
    for (int i = 0; i < 16; ++i){ acc0[i] = 0.f; acc1[i] = 0.f; accS[i] = 0.f; }

    short8 ones;
#pragma unroll
    for (int i = 0; i < 8; ++i) ones[i] = (short)0x3F80;  // bf16 1.0

    // wave w owns output c-tiles 2w and 2w+1
    const int c_a = (2 * w) * 32 + l31;
    const int c_b = c_a + 32;

    for (int tile = 0; tile < TILES; ++tile){
        const int n0 = blockIdx.x * (TILES * 128) + tile * 128;
        __syncthreads();   // protect xs/aws from previous tile's MFMA readers

        // ---- phase 1: stream x (depth-2 x 8-wide prefetch), fp32 dots, stage bf16 ----
        const float* xp = xb + n0 + t;

        float xc[K_DIM];
#pragma unroll
        for (int k = 0; k < K_DIM; ++k) xc[k] = 0.f;
        float x2 = 0.f;

        float cur[8], nx1[8];
#pragma unroll
        for (int j = 0; j < 8; ++j) cur[j] = xp[j * N_SP];
#pragma unroll
        for (int j = 0; j < 8; ++j) nx1[j] = xp[(8 + j) * N_SP];

#pragma unroll 1
        for (int g = 0; g < 14; ++g){
            float nx2[8];
#pragma unroll
            for (int j = 0; j < 8; ++j)           // issue g+2's loads first
                nx2[j] = xp[((g + 2) * 8 + j) * N_SP];
#pragma unroll
            for (int j = 0; j < 8; ++j){
                const int c = g * 8 + j;
                const float xv = cur[j];
                x2 = fmaf(xv, xv, x2);
                xs[SWZ(c, t)] = f2bf(xv);
                const float* cwc = cwt2 + (c << 5);   // wave-uniform -> s_load
#pragma unroll
                for (int k = 0; k < K_DIM; ++k)
                    xc[k] = fmaf(xv, cwc[k], xc[k]);
            }
#pragma unroll
            for (int j = 0; j < 8; ++j){ cur[j] = nx1[j]; nx1[j] = nx2[j]; }
        }
        // epilogue groups 14, 15 (already loaded)
#pragma unroll
        for (int gg = 14; gg < 16; ++gg){
#pragma unroll
            for (int j = 0; j < 8; ++j){
                const int c = gg * 8 + j;
                const float xv = cur[j];
                x2 = fmaf(xv, xv, x2);
                xs[SWZ(c, t)] = f2bf(xv);
                const float* cwc = cwt2 + (c << 5);
#pragma unroll
                for (int k = 0; k < K_DIM; ++k)
                    xc[k] = fmaf(xv, cwc[k], xc[k]);
            }
#pragma unroll
            for (int j = 0; j < 8; ++j) cur[j] = nx1[j];
        }

        // ---- phase 2: per-thread softmax over k ----
        float m = -3.4e38f;
#pragma unroll
        for (int k = 0; k < K_DIM; ++k){
            float s = fmaf(scale[k], x2, xc[k] + sc2[k]);  // scale*(x2 - 2x.cw + c2)
            xc[k] = s;
            m = fmaxf(m, s);
        }
        float sum = 0.f;
#pragma unroll
        for (int k = 0; k < K_DIM; ++k){
            float p = __expf(xc[k] - m);
            xc[k] = p;
            sum += p;
        }
        float r = 1.f / sum;
#pragma unroll
        for (int k = 0; k < K_DIM; ++k)
            aws[SWZ(k, t)] = f2bf(xc[k] * r);

        __syncthreads();

        // ---- phase 3: wx[k][c] += aw[k][n] * x[n][c] via MFMA (acc across tiles) ----
#pragma unroll
        for (int nch = 0; nch < 8; ++nch){
            const int n8 = nch * 16 + hi * 8;   // K-dim (n) elems for this lane
            short8 af  = *(const short8*)(const void*)&aws[SWZ(l31, n8)];
            short8 bf0 = *(const short8*)(const void*)&xs[SWZ(c_a, n8)];
            short8 bf1 = *(const short8*)(const void*)&xs[SWZ(c_b, n8)];
            acc0 = __builtin_amdgcn_mfma_f32_32x32x16_bf16(af, bf0, acc0, 0, 0, 0);
            acc1 = __builtin_amdgcn_mfma_f32_32x32x16_bf16(af, bf1, acc1, 0, 0, 0);
            if (w == 0)
                accS = __builtin_amdgcn_mfma_f32_32x32x16_bf16(af, ones, accS, 0, 0, 0);
        }
    }

    // ---- epilogue: atomic-reduce block partials to global ----
    float* wxb = wxacc + (size_t)b * K_DIM * C_DIM;
#pragma unroll
    for (int rg = 0; rg < 16; ++rg){
        const int row = (rg & 3) + 8 * (rg >> 2) + 4 * hi;  // verified D layout
        atomicAdd(&wxb[row * C_DIM + c_a], acc0[rg]);
        atomicAdd(&wxb[row * C_DIM + c_b], acc1[rg]);
    }
    if (w == 0 && l31 == 0){
#pragma unroll
        for (int rg = 0; rg < 16; ++rg){
            const int row = (rg & 3) + 8 * (rg >> 2) + 4 * hi;
            atomicAdd(&wsacc[b * K_DIM + row], accS[rg]);
        }
    }
}

__global__ void enc_prep(const float* __restrict__ cw, const float* __restrict__ scale,
                         float* __restrict__ cwt2, float* __restrict__ sc2){
    const int t = threadIdx.x;  // 128 threads; t = c
    for (int k = 0; k < K_DIM; ++k)
        cwt2[t * K_DIM + k] = -2.f * scale[k] * cw[k * C_DIM + t];
    if (t < K_DIM){
        float s = 0.f;
        for (int c = 0; c < C_DIM; ++c){
            float v = cw[t * C_DIM + c];
            s = fmaf(v, v, s);
        }
        sc2[t] = scale[t] * s;
    }
}

__global__ void enc_final(const float* __restrict__ wxacc, const float* __restrict__ wsacc,
                          const float* __restrict__ cw, float* __restrict__ out){
    const int i  = blockIdx.x * 256 + threadIdx.x;  // B*K*C = 131072
    const int c  = i & (C_DIM - 1);
    const int kk = (i >> 7) & (K_DIM - 1);
    const int bk = i >> 7;
    out[i] = wxacc[i] - wsacc[bk] * cw[kk * C_DIM + c];
}

extern "C" void kernel_launch(void* const* d_in, const int* in_sizes, int n_in,
                              void* d_out, int out_size, void* d_ws, size_t ws_size,
                              hipStream_t stream){
    (void)in_sizes; (void)n_in; (void)out_size; (void)ws_size;
    const float* x     = (const float*)d_in[0];
    const float* cw    = (const float*)d_in[1];
    const float* scale = (const float*)d_in[2];
    float* out = (float*)d_out;

    float* wxacc = (float*)d_ws;                 // 32*32*128 f32
    float* wsacc = wxacc + 32 * 32 * 128;        // 32*32
    float* cwt2  = wsacc + 32 * 32;              // 128*32
    float* sc2   = cwt2 + 128 * 32;              // 32

    hipMemsetAsync(wxacc, 0, (32 * 32 * 128 + 32 * 32) * sizeof(float), stream);
    enc_prep<<<1, 128, 0, stream>>>(cw, scale, cwt2, sc2);
    enc_main<<<dim3(NBX, 32), 128, 0, stream>>>(x, cwt2, scale, sc2, wxacc, wsacc);
    enc_final<<<512, 256, 0, stream>>>(wxacc, wsacc, cw, out);
}